// Round 14
// baseline (193.138 us; speedup 1.0000x reference)
//
#include <hip/hip_runtime.h>
#include <math.h>

#define B_   16
#define L_   128
#define O_   128
#define N_   256
#define S_   64
#define U_   32
#define DEL_ 64
#define HID_ 512
#define CH_  288          // N_+U_
#define M_   2048         // B_*L_
#define KD_  288          // GEMM K for the Wg projections
#define CM_BASE (DEL_ + N_*U_)   // 8256
#define NSLICE 32

typedef __bf16 bf16_t;
typedef bf16_t bf16x8 __attribute__((ext_vector_type(8)));
typedef float  f32x4  __attribute__((ext_vector_type(4)));

#define AS1(p) ((const __attribute__((address_space(1))) void*)(unsigned long long)(const void*)(p))
#define AS3(p) ((__attribute__((address_space(3))) void*)(unsigned int)(unsigned long long)(const void*)(p))

__device__ __forceinline__ float silu_f(float x){ return x / (1.f + expf(-x)); }
__device__ __forceinline__ float softplus_f(float x){
  return fmaxf(x, 0.f) + log1pf(expf(-fabsf(x)));
}

__device__ __forceinline__ void cvt8(const float* src, bf16_t* dst){
  float4 a = ((const float4*)src)[0];
  float4 b = ((const float4*)src)[1];
  bf16x8 o;
  o[0]=(bf16_t)a.x; o[1]=(bf16_t)a.y; o[2]=(bf16_t)a.z; o[3]=(bf16_t)a.w;
  o[4]=(bf16_t)b.x; o[5]=(bf16_t)b.y; o[6]=(bf16_t)b.z; o[7]=(bf16_t)b.w;
  *(bf16x8*)dst = o;
}

// ---------------- prep: Wg/W0/W1->bf16, x->bf16 packed, WgdT+WdtT transposes ----------------
#define CVT_BLOCKS 3465    // ceil(887040/256)  (Wg chunks of 8)
#define W0_BLOCKS  16      // 4096 chunks
#define W1_BLOCKS  64      // 16384 chunks
#define XB_BLOCKS  64      // 16384 chunks
#define WGT_BLOCKS 72      // 18432 elements: WgdT[288][64] = Wg[0:64][0:288]^T (delta slice)
#define WDT_BLOCKS 64      // 16384 elements: WdtT[64][256] = Wdt[256][64]^T
__global__ void k_prep(const float* __restrict__ Wg, bf16_t* __restrict__ Wgbf,
                       const float* __restrict__ W0, bf16_t* __restrict__ W0bf,
                       const float* __restrict__ W1, bf16_t* __restrict__ W1bf,
                       const float* __restrict__ x,  bf16_t* __restrict__ xbf,
                       const float* __restrict__ Wdt, float* __restrict__ WdtT,
                       float* __restrict__ WgdT, float* __restrict__ lossa){
  if (blockIdx.x == 0 && threadIdx.x < 2) lossa[threadIdx.x] = 0.f;
  if (blockIdx.x < CVT_BLOCKS) {
    int i = blockIdx.x*256 + threadIdx.x;
    if (i >= 887040) return;
    cvt8(Wg + (size_t)i*8, Wgbf + (size_t)i*8);
  } else if (blockIdx.x < CVT_BLOCKS + W0_BLOCKS) {
    int i = (blockIdx.x - CVT_BLOCKS)*256 + threadIdx.x;
    if (i >= 4096) return;
    cvt8(W0 + (size_t)i*8, W0bf + (size_t)i*8);
  } else if (blockIdx.x < CVT_BLOCKS + W0_BLOCKS + W1_BLOCKS) {
    int i = (blockIdx.x - CVT_BLOCKS - W0_BLOCKS)*256 + threadIdx.x;
    if (i >= 16384) return;
    cvt8(W1 + (size_t)i*8, W1bf + (size_t)i*8);
  } else if (blockIdx.x < CVT_BLOCKS + W0_BLOCKS + W1_BLOCKS + XB_BLOCKS) {
    int i = (blockIdx.x - CVT_BLOCKS - W0_BLOCKS - W1_BLOCKS)*256 + threadIdx.x;
    if (i >= 16384) return;
    int m = i >> 3, c0 = (i & 7)*8;
    int b = m >> 7, t = m & 127;
    cvt8(x + (size_t)(((b<<8)+t)<<6) + c0, xbf + (size_t)m*64 + c0);
  } else if (blockIdx.x < CVT_BLOCKS + W0_BLOCKS + W1_BLOCKS + XB_BLOCKS + WGT_BLOCKS) {
    // delta-slice transpose: WgdT[k][d] = Wg[d][k], d<64, k<288 (coalesced read)
    int i = (blockIdx.x - CVT_BLOCKS - W0_BLOCKS - W1_BLOCKS - XB_BLOCKS)*256 + threadIdx.x;
    if (i >= 18432) return;
    int d = i / KD_, k = i - d*KD_;
    WgdT[k*64 + d] = Wg[(size_t)d*KD_ + k];
  } else {
    // Wdt transpose: WdtT[d][n] = Wdt[n][d] (write coalesced)
    int i = (blockIdx.x - CVT_BLOCKS - W0_BLOCKS - W1_BLOCKS - XB_BLOCKS - WGT_BLOCKS)*256 + threadIdx.x;
    if (i >= 16384) return;
    int d = i >> 8, n = i & 255;
    WdtT[i] = Wdt[(size_t)n*64 + d];
  }
}

// ---- 64-row tile stage, one 16-row group per wave, arbitrary K offset ----
#define STAGE64K(GBASE, ROW0G, STRIDE, KK, LDSP)                                     \
  { const bf16_t* gp_ = (GBASE) + (size_t)((ROW0G) + wave*16 + lm)*(STRIDE) + (KK) + lq*8; \
    __builtin_amdgcn_global_load_lds(AS1(gp_), AS3((LDSP) + wave*512), 16, 0, 0); }

// ---- 64-row tile stage, BK=128 in fragment order (4 k-subblocks of 32) ----
#define STAGE128(GBASE, ROW0G, STRIDE, TT, BUF)                                      \
  { _Pragma("unroll")                                                                \
    for (int kb_ = 0; kb_ < 4; kb_++) {                                              \
      const bf16_t* gp_ = (GBASE) + (size_t)((ROW0G) + wave*16 + lm)*(STRIDE)        \
                          + (TT)*128 + kb_*32 + lq*8;                                \
      __builtin_amdgcn_global_load_lds(AS1(gp_), AS3((BUF) + kb_*2048 + wave*512), 16, 0, 0);\
    } }

// ---- 128-row tile stage, BK=32: two 16-row groups per wave (one 8 KB chunk) ----
#define STAGE32(GBASE, ROW0G, KK, LDSP)                                              \
  { _Pragma("unroll")                                                                \
    for (int l_ = 0; l_ < 2; l_++) {                                                 \
      int g_ = wave*2 + l_;                                                          \
      const bf16_t* gp_ = (GBASE) + (size_t)((ROW0G) + g_*16 + lm)*KD_ + (KK) + lq*8;\
      __builtin_amdgcn_global_load_lds(AS1(gp_), AS3((LDSP) + g_*512), 16, 0, 0);    \
    } }

// ---- 128-row tile stage, BK=96 (3 col-blocks of 32) ----
#define STAGE_FR96(GBASE, ROW0G, KK, LDSP)                                           \
  { _Pragma("unroll")                                                                \
    for (int c_ = 0; c_ < 3; c_++) {                                                 \
      _Pragma("unroll")                                                              \
      for (int q_ = 0; q_ < 2; q_++) {                                               \
        int g_ = wave*2 + q_;                                                        \
        const bf16_t* gp_ = (GBASE) + (size_t)((ROW0G) + g_*16 + lm)*KD_ + (KK) + c_*32 + lq*8;\
        __builtin_amdgcn_global_load_lds(AS1(gp_), AS3((LDSP) + c_*4096 + g_*512), 16, 0, 0);\
      } } }

// ---------------- mlp1 MFMA: Hbf = relu(xbf @ W0bf.T + b0), K=64, 2-phase ----------------
__global__ __launch_bounds__(256) void k_mlp1m(
    const bf16_t* __restrict__ xbf, const bf16_t* __restrict__ W0bf,
    const float* __restrict__ b0, bf16_t* __restrict__ Hbf){
  __shared__ __align__(16) bf16_t As[2][2048];
  __shared__ __align__(16) bf16_t Bs[2][2048];
  int tid = threadIdx.x;
  int wave = tid >> 6, lane = tid & 63;
  int wm = wave & 1, wn = wave >> 1;
  int nt = blockIdx.x, mt = blockIdx.y;
  int m0 = mt*64, n0 = nt*64;
  int lm = lane & 15, lq = lane >> 4;

  f32x4 acc[2][2];
  #pragma unroll
  for (int i=0;i<2;i++)
    #pragma unroll
    for (int j=0;j<2;j++){ acc[i][j][0]=0.f;acc[i][j][1]=0.f;acc[i][j][2]=0.f;acc[i][j][3]=0.f; }

  STAGE64K(xbf,  m0, 64, 0, As[0]);
  STAGE64K(W0bf, n0, 64, 0, Bs[0]);
  __syncthreads();
  #pragma unroll
  for (int t = 0; t < 2; ++t) {
    int cur = t & 1;
    if (t < 1) {
      STAGE64K(xbf,  m0, 64, 32, As[1]);
      STAGE64K(W0bf, n0, 64, 32, Bs[1]);
    }
    bf16x8 af[2], bff[2];
    #pragma unroll
    for (int i=0;i<2;i++) af[i]  = *(const bf16x8*)&As[cur][(wm*2 + i)*512 + lane*8];
    #pragma unroll
    for (int j=0;j<2;j++) bff[j] = *(const bf16x8*)&Bs[cur][(wn*2 + j)*512 + lane*8];
    #pragma unroll
    for (int i=0;i<2;i++)
      #pragma unroll
      for (int j=0;j<2;j++)
        acc[i][j] = __builtin_amdgcn_mfma_f32_16x16x32_bf16(af[i], bff[j], acc[i][j], 0,0,0);
    __syncthreads();
  }
  #pragma unroll
  for (int i=0;i<2;i++)
    #pragma unroll
    for (int j=0;j<2;j++){
      int col = n0 + wn*32 + j*16 + lm;
      float bb = b0[col];
      #pragma unroll
      for (int r=0;r<4;r++){
        int row = m0 + wm*32 + i*16 + lq*4 + r;
        Hbf[(size_t)row*HID_ + col] = (bf16_t)fmaxf(acc[i][j][r] + bb, 0.f);
      }
    }
}

// ---------------- mlp2 MFMA: P = Hbf @ W1bf.T + b1, split-K x2 (R14) ----------------
// R14: grid (4, 32, 2) = 256 blocks (was 128 -> half the CUs idle). Each z-half
// computes K=256 into its own buffer P + kz*524288; consumers sum the halves.
// b1 added only in half 0.
__global__ __launch_bounds__(256) void k_mlp2m(
    const bf16_t* __restrict__ Hbf, const bf16_t* __restrict__ W1bf,
    const float* __restrict__ b1, float* __restrict__ P){
  __shared__ __align__(16) bf16_t As[2][8192];
  __shared__ __align__(16) bf16_t Bs[2][8192];
  int tid = threadIdx.x;
  int wave = tid >> 6, lane = tid & 63;
  int wm = wave & 1, wn = wave >> 1;
  int nt = blockIdx.x, mt = blockIdx.y, kz = blockIdx.z;
  int m0 = mt*64, n0 = nt*64;
  int lm = lane & 15, lq = lane >> 4;

  f32x4 acc[2][2];
  #pragma unroll
  for (int i=0;i<2;i++)
    #pragma unroll
    for (int j=0;j<2;j++){ acc[i][j][0]=0.f;acc[i][j][1]=0.f;acc[i][j][2]=0.f;acc[i][j][3]=0.f; }

  STAGE128(Hbf,  m0, HID_, kz*2, As[0]);
  STAGE128(W1bf, n0, HID_, kz*2, Bs[0]);
  __syncthreads();
  #pragma unroll
  for (int t = 0; t < 2; ++t) {
    int cur = t & 1;
    if (t < 1) {
      STAGE128(Hbf,  m0, HID_, kz*2 + 1, As[cur^1]);
      STAGE128(W1bf, n0, HID_, kz*2 + 1, Bs[cur^1]);
    }
    #pragma unroll
    for (int kb = 0; kb < 4; kb++) {
      bf16x8 af[2], bff[2];
      #pragma unroll
      for (int i=0;i<2;i++) af[i]  = *(const bf16x8*)&As[cur][kb*2048 + (wm*2 + i)*512 + lane*8];
      #pragma unroll
      for (int j=0;j<2;j++) bff[j] = *(const bf16x8*)&Bs[cur][kb*2048 + (wn*2 + j)*512 + lane*8];
      #pragma unroll
      for (int i=0;i<2;i++)
        #pragma unroll
        for (int j=0;j<2;j++)
          acc[i][j] = __builtin_amdgcn_mfma_f32_16x16x32_bf16(af[i], bff[j], acc[i][j], 0,0,0);
    }
    __syncthreads();
  }
  float* Pz = P + (size_t)kz*(M_*N_);
  #pragma unroll
  for (int i=0;i<2;i++)
    #pragma unroll
    for (int j=0;j<2;j++){
      int col = n0 + wn*32 + j*16 + lm;
      float bb = (kz == 0) ? b1[col] : 0.f;
      #pragma unroll
      for (int r=0;r<4;r++){
        int row = m0 + wm*32 + i*16 + lq*4 + r;
        Pz[(size_t)row*N_ + col] = acc[i][j][r] + bb;
      }
    }
}

// ---------------- fused conv + delta, 4 rows/block (512 blocks) ----------------
// R14: P is split-K pair (P, P2=P+M_*N_); sum on read.
__global__ __launch_bounds__(256) void k_convdelta(
    const float* __restrict__ P, const float* __restrict__ u,
    const float* __restrict__ cw, const float* __restrict__ cb,
    const float* __restrict__ WgdT, const float* __restrict__ bg,
    const float* __restrict__ WdtT, const float* __restrict__ bdt,
    const float* __restrict__ Ap, bf16_t* __restrict__ oldbf,
    float* __restrict__ dA, float* __restrict__ coef){
  __shared__ __align__(16) float olds[4*KD_];
  __shared__ float dr[4][64];
  int tid = threadIdx.x;
  int m0 = blockIdx.x * 4;
  int b = m0 >> 7, l0 = m0 & 127;
  const float* P2 = P + (size_t)M_*N_;
  for (int e = tid; e < 4*CH_; e += 256) {
    int r = e / CH_, c = e - r*CH_;
    int l = l0 + r;
    float acc = cb[c];
    #pragma unroll
    for (int k = 0; k < 4; k++) {
      int t = l + k - 1;
      if (t >= 0 && t <= O_-2) {
        int pi = ((b<<7)+t)*N_ + c;
        float s = (c < N_) ? (P[pi] + P2[pi]) : u[((b<<8)+t)*U_ + (c-N_)];
        acc += silu_f(s) * cw[c*4 + k];
      }
    }
    float v = silu_f(acc);
    olds[e] = v;
    oldbf[(size_t)(m0+r)*CH_ + c] = (bf16_t)v;
  }
  __syncthreads();
  {
    int d = tid & 63;
    int r = tid >> 6;
    const float* wcol = WgdT + d;          // column d of WgdT[288][64]
    const float* orow = olds + r*KD_;
    float s = 0.f;
    for (int k = 0; k < KD_; k++) s += orow[k] * wcol[k*64];   // lanes coalesce per k
    dr[r][d] = s + bg[d];
  }
  __syncthreads();
  int n = tid;
  float wrow[64];
  #pragma unroll
  for (int d = 0; d < 64; d++) wrow[d] = WdtT[d*256 + n];   // coalesced: lanes consecutive
  float a0 = Ap[n];
  float a = -(a0 > 0.f ? a0 : expm1f(a0));
  float inva = 1.f / a;
  float bd = bdt[n];
  #pragma unroll
  for (int r = 0; r < 4; r++) {
    float s = bd;
    #pragma unroll
    for (int d = 0; d < 64; d++) s += dr[r][d] * wrow[d];   // dr: wave-broadcast
    float dd = softplus_f(s);
    float e  = expf(dd * a);
    size_t m = m0 + r;
    dA[m*N_ + n]   = e;
    coef[m*N_ + n] = (e - 1.f) * inva;
  }
}

// ---------------- B-path MFMA v3b: ring-3 counted-vmcnt, LDS 48 KB, LB(256,2) ----------------
__global__ __launch_bounds__(256, 2) void k_bmfma(
    const bf16_t* __restrict__ oldbf, const bf16_t* __restrict__ Wgbf,
    const float* __restrict__ bg, const float* __restrict__ u,
    const float* __restrict__ coef, const float* __restrict__ dAg,
    const float* __restrict__ Pg, float* __restrict__ zall){
  __shared__ union {
    struct { __align__(16) bf16_t A[3][4096]; __align__(16) bf16_t B[3][4096]; } st; // 48 KB
    struct { float wl[128][4]; float dal[128][4]; } sc;   // 4 KB, used post-GEMM
  } sm;
  int tid = threadIdx.x;
  int wave = tid >> 6, lane = tid & 63;
  int wm = wave & 1, wn = wave >> 1;
  int mt = blockIdx.y, nt = blockIdx.x;
  int m0 = mt*128, ncol0 = nt*128;
  int lm = lane & 15, lq = lane >> 4;

  f32x4 acc[4][4];
  #pragma unroll
  for (int i=0;i<4;i++)
    #pragma unroll
    for (int j=0;j<4;j++){ acc[i][j][0]=0.f;acc[i][j][1]=0.f;acc[i][j][2]=0.f;acc[i][j][3]=0.f; }

  // prologue: issue steps 0,1 (8 loads in flight)
  STAGE32(oldbf, m0, 0, sm.st.A[0]);
  STAGE32(Wgbf, DEL_ + ncol0, 0, sm.st.B[0]);
  STAGE32(oldbf, m0, 32, sm.st.A[1]);
  STAGE32(Wgbf, DEL_ + ncol0, 32, sm.st.B[1]);
  #pragma unroll
  for (int t = 0; t < 9; ++t) {             // 288/32 = 9 K-steps
    if (t < 8) { asm volatile("s_waitcnt vmcnt(4)" ::: "memory"); }  // step t done, t+1 in flight
    else       { asm volatile("s_waitcnt vmcnt(0)" ::: "memory"); }
    __builtin_amdgcn_s_barrier();           // step t visible; slot (t+2)%3 readers done
    if (t + 2 < 9) {                        // issue step t+2 into ring slot
      int kk = (t+2)*32;
      STAGE32(oldbf, m0, kk, sm.st.A[(t+2)%3]);
      STAGE32(Wgbf, DEL_ + ncol0, kk, sm.st.B[(t+2)%3]);
    }
    bf16x8 af[4], bff[4];
    #pragma unroll
    for (int i=0;i<4;i++) af[i]  = *(const bf16x8*)&sm.st.A[t%3][(wm*4 + i)*512 + lane*8];
    #pragma unroll
    for (int j=0;j<4;j++) bff[j] = *(const bf16x8*)&sm.st.B[t%3][(wn*4 + j)*512 + lane*8];
    __builtin_amdgcn_s_setprio(1);          // T5: favor MFMA-issuing wave
    #pragma unroll
    for (int i=0;i<4;i++)
      #pragma unroll
      for (int j=0;j<4;j++)
        acc[i][j] = __builtin_amdgcn_mfma_f32_16x16x32_bf16(af[i], bff[j], acc[i][j], 0,0,0);
    __builtin_amdgcn_s_setprio(0);
  }
  __syncthreads();                          // all st readers done before sc overlay

  // staging LDS dead: preload dA columns for the fused scan
  for (int e = tid; e < 512; e += 256)
    sm.sc.dal[e>>2][e&3] = dAg[(size_t)(m0 + (e>>2))*N_ + nt*4 + (e&3)];

  float bgv[4];
  #pragma unroll
  for (int j=0;j<4;j++) bgv[j] = bg[DEL_ + ncol0 + wn*64 + j*16 + lm];
  float p[2][4][4];
  #pragma unroll
  for (int a=0;a<2;a++)
    #pragma unroll
    for (int i=0;i<4;i++)
      #pragma unroll
      for (int r=0;r<4;r++) p[a][i][r]=0.f;
  #pragma unroll
  for (int i=0;i<4;i++){
    #pragma unroll
    for (int r=0;r<4;r++){
      int m = m0 + wm*64 + i*16 + lq*4 + r;
      int b = m >> 7, l = m & 127;
      const float* urow = u + ((size_t)(b<<8) + 127 + l)*U_;
      #pragma unroll
      for (int j=0;j<4;j++){
        float uu = urow[(j&1)*16 + lm];
        p[j>>1][i][r] += (acc[i][j][r] + bgv[j]) * uu;
      }
    }
  }
  #pragma unroll
  for (int mk = 1; mk < 16; mk <<= 1){
    #pragma unroll
    for (int a=0;a<2;a++)
      #pragma unroll
      for (int i=0;i<4;i++)
        #pragma unroll
        for (int r=0;r<4;r++) p[a][i][r] += __shfl_xor(p[a][i][r], mk);
  }
  if (lm == 0){
    #pragma unroll
    for (int nl=0;nl<2;nl++){
      int n = ((ncol0 + wn*64 + nl*32) >> 5);
      int nc = wn*2 + nl;
      #pragma unroll
      for (int i=0;i<4;i++)
        #pragma unroll
        for (int r=0;r<4;r++){
          int l = wm*64 + i*16 + lq*4 + r;
          sm.sc.wl[l][nc] = coef[(size_t)(m0+l)*N_ + n] * p[nl][i][r];
        }
    }
  }
  __syncthreads();

  // fused scan: wave = n-column; 2 l per lane, Kogge-Stone over pair affines
  {
    int nc = wave;
    int n = nt*4 + nc;
    size_t zi = (size_t)(m0 + 127)*N_ + n;
    float z0 = Pg[zi] + Pg[zi + (size_t)M_*N_];   // split-K halves summed
    int l0 = lane*2;
    float a0 = sm.sc.dal[l0][nc],   w0 = sm.sc.wl[l0][nc];
    float a1 = sm.sc.dal[l0+1][nc], w1 = sm.sc.wl[l0+1][nc];
    float A = a0*a1, Bv = w0*a1 + w1;
    #pragma unroll
    for (int d = 1; d < 64; d <<= 1){
      float Ap = __shfl_up(A, d);
      float Bp = __shfl_up(Bv, d);
      if (lane >= d){ Bv = Bp*A + Bv; A = Ap*A; }
    }
    float Ae = __shfl_up(A, 1);
    float Be = __shfl_up(Bv, 1);
    if (lane == 0){ Ae = 1.f; Be = 0.f; }
    float zp = z0*Ae + Be;
    float za = zp*a0 + w0;
    float zb = za*a1 + w1;
    zall[(size_t)(m0 + l0)*N_ + n]     = za;
    zall[(size_t)(m0 + l0 + 1)*N_ + n] = zb;
  }
}

// ---------------- C-path MFMA v7b: ring-3 counted-vmcnt, LDS 52 KB, LB(256,2) ----------------
__global__ __launch_bounds__(256, 2) void k_cmfma(
    const bf16_t* __restrict__ oldbf, const bf16_t* __restrict__ Wgbf,
    const float* __restrict__ bg, const float* __restrict__ zall,
    float* __restrict__ ypart){
  __shared__ union {
    struct { __align__(16) bf16_t A[3*4096];   // 24 KB, resident per kh
             __align__(16) bf16_t Bb[3][4096]; // 24 KB, 3-deep chunk ring
             float zl[128][8]; } st;           // 4 KB  -> 52 KB total
    float ylds[128][64];                        // 32 KB, used at the end
  } sm;
  int tid = threadIdx.x;
  int wave = tid >> 6, lane = tid & 63;
  int wm = wave & 1, wn = wave >> 1;
  int mt = blockIdx.y, grp = blockIdx.x;   // 32 groups of 4 n-tiles
  int m0 = mt*128;
  int lm = lane & 15, lq = lane >> 4;

  // preload z block: 128 m x 8 n
  for (int e = tid; e < 1024; e += 256)
    sm.st.zl[e>>3][e&7] = zall[(size_t)(m0 + (e>>3))*N_ + grp*8 + (e&7)];

  f32x4 yacc[4][4];
  #pragma unroll
  for (int i=0;i<4;i++)
    #pragma unroll
    for (int j=0;j<4;j++){ yacc[i][j][0]=0.f;yacc[i][j][1]=0.f;yacc[i][j][2]=0.f;yacc[i][j][3]=0.f; }

  f32x4 acc[4][4];
  for (int kh = 0; kh < 3; kh++) {
    int kk = kh*96;
    if (kh) __builtin_amdgcn_s_barrier();        // all A/Bb readers of prev kh done
    STAGE_FR96(oldbf, m0, kk, sm.st.A);          // 6 loads
    STAGE32(Wgbf, CM_BASE + (grp*4)*128, kk,      sm.st.Bb[0]);  // chunk 0 (2 loads)
    STAGE32(Wgbf, CM_BASE + (grp*4)*128, kk + 32, sm.st.Bb[1]);  // chunk 1 (2 loads)

    #pragma unroll
    for (int c = 0; c < 12; ++c) {               // chunk = (it = c/3, cb = c%3)
      int it = c/3, cb = c%3;
      // c=0: completes A+chunk0 (chunk1 in flight); c=1..10: completes chunk c; c=11: drain
      if (c < 11) { asm volatile("s_waitcnt vmcnt(2)" ::: "memory"); }
      else        { asm volatile("s_waitcnt vmcnt(0)" ::: "memory"); }
      __builtin_amdgcn_s_barrier();              // chunk c visible; slot (c+2)%3 readers done
      if (c + 2 < 12) {
        int c2 = c + 2, it2 = c2/3, cb2 = c2%3;
        STAGE32(Wgbf, CM_BASE + (grp*4 + it2)*128, kk + cb2*32, sm.st.Bb[c2 % 3]);
      }
      if (cb == 0) {
        #pragma unroll
        for (int i=0;i<4;i++)
          #pragma unroll
          for (int j=0;j<4;j++){ acc[i][j][0]=0.f;acc[i][j][1]=0.f;acc[i][j][2]=0.f;acc[i][j][3]=0.f; }
      }
      bf16x8 af[4], bff[4];
      #pragma unroll
      for (int i=0;i<4;i++) af[i]  = *(const bf16x8*)&sm.st.A[cb*4096 + (wm*4 + i)*512 + lane*8];
      #pragma unroll
      for (int j=0;j<4;j++) bff[j] = *(const bf16x8*)&sm.st.Bb[c % 3][(wn*4 + j)*512 + lane*8];
      __builtin_amdgcn_s_setprio(1);
      #pragma unroll
      for (int i=0;i<4;i++)
        #pragma unroll
        for (int j=0;j<4;j++)
          acc[i][j] = __builtin_amdgcn_mfma_f32_16x16x32_bf16(af[i], bff[j], acc[i][j], 0,0,0);
      __builtin_amdgcn_s_setprio(0);
      if (cb == 2) {
        // it's full-K gen tile done: contract with z (bg only on last kh)
        int ncol0 = (grp*4 + it)*128;
        int nl = it*2 + wn;
        float bgv[4];
        #pragma unroll
        for (int j=0;j<4;j++)
          bgv[j] = (kh == 2) ? bg[CM_BASE + ncol0 + wn*64 + j*16 + lm] : 0.f;
        #pragma unroll
        for (int i=0;i<4;i++){
          #pragma unroll
          for (int r=0;r<4;r++){
            float zv = sm.st.zl[wm*64 + i*16 + lq*4 + r][nl];
            #pragma unroll
            for (int j=0;j<4;j++)
              yacc[i][j][r] += (acc[i][j][r] + bgv[j]) * zv;
          }
        }
      }
    }
  }

  __builtin_amdgcn_s_barrier();   // all st readers done before ylds overlay
  // merge the two wn halves through ylds (overlays staging LDS), then store slice
  if (wn == 1){
    #pragma unroll
    for (int i=0;i<4;i++)
      #pragma unroll
      for (int j=0;j<4;j++)
        #pragma unroll
        for (int r=0;r<4;r++){
          int ml = wm*64 + i*16 + lq*4 + r;
          sm.ylds[ml][j*16 + lm] = yacc[i][j][r];
        }
  }
  __syncthreads();
  if (wn == 0){
    float* dst = ypart + (size_t)grp*(M_*S_);
    #pragma unroll
    for (int i=0;i<4;i++)
      #pragma unroll
      for (int j=0;j<4;j++)
        #pragma unroll
        for (int r=0;r<4;r++){
          int ml = wm*64 + i*16 + lq*4 + r;
          int s = j*16 + lm;
          dst[(size_t)(m0+ml)*S_ + s] = yacc[i][j][r] + sm.ylds[ml][s];
        }
  }
}

// ---------------- finalize: sum slices, write ys (L,B,S), fused loss ----------------
// R14: 512 blocks x 1 elem/thread (was 256 x 2) -> 2x waves in flight for the
// 32-deep latency-bound gather.
__global__ void k_finalize(const float* __restrict__ ypart, const float* __restrict__ x,
                           float* __restrict__ out, float* __restrict__ lossacc){
  __shared__ float red[256];
  int tid = threadIdx.x;
  int e = blockIdx.x*256 + tid;
  int m = e >> 6, s = e & 63;
  int b = m >> 7, l = m & 127;
  float yv = 0.f;
  #pragma unroll 8
  for (int g = 0; g < NSLICE; g++) yv += ypart[(size_t)g*(M_*S_) + e];
  out[1 + (size_t)((l<<4) + b)*S_ + s] = yv;
  float xv = x[((size_t)(b<<8) + 128 + l)*S_ + s];
  float d = yv - xv;
  float ls = d*d;
  red[tid] = ls; __syncthreads();
  for (int st = 128; st > 0; st >>= 1) {
    if (tid < st) red[tid] += red[tid+st];
    __syncthreads();
  }
  if (tid == 0) {
    atomicAdd(&lossacc[0], red[0]);
    __threadfence();
    unsigned old = atomicAdd((unsigned*)&lossacc[1], 1u);
    if (old == 511u) {
      float tot = atomicAdd(&lossacc[0], 0.f);   // atomic read (bypass L1)
      out[0] = tot * (1.f / (float)(B_*S_*L_));
    }
  }
}

extern "C" void kernel_launch(void* const* d_in, const int* in_sizes, int n_in,
                              void* d_out, int out_size, void* d_ws, size_t ws_size,
                              hipStream_t stream) {
  const float* x   = (const float*)d_in[0];
  const float* u   = (const float*)d_in[1];
  const float* Ap  = (const float*)d_in[2];
  const float* W0  = (const float*)d_in[3];
  const float* b0  = (const float*)d_in[4];
  const float* W1  = (const float*)d_in[5];
  const float* b1  = (const float*)d_in[6];
  const float* cw  = (const float*)d_in[7];
  const float* cb  = (const float*)d_in[8];
  const float* Wg  = (const float*)d_in[9];
  const float* bg  = (const float*)d_in[10];
  const float* Wdt = (const float*)d_in[11];
  const float* bdt = (const float*)d_in[12];
  float* out = (float*)d_out;

  // Layout: persistent buffers first; region R of fp32 temps (all dead before
  // k_cmfma) is overlaid by ypart (32 slices = 16 MB). WgdT/WdtT past ypart's span.
  // R14: Pp is a split-K pair (2 x 524288); dA/coef follow. ypart (4194304)
  // overlays Pp[0]+Pp[1]+dA+coef exactly.
  float* ws    = (float*)d_ws;
  float* zall  = ws;                        // 524288
  float* lossa = zall + 524288;             // 512 (acc, counter)
  bf16_t* oldbf = (bf16_t*)(lossa + 512);   // 294912 f32 slots
  bf16_t* Wgbf  = (bf16_t*)(lossa + 512 + 294912);              // 3548160 slots
  bf16_t* W0bf  = (bf16_t*)(lossa + 512 + 294912 + 3548160);    // 16384 slots
  bf16_t* W1bf  = (bf16_t*)(lossa + 512 + 294912 + 3548160 + 16384);   // 65536 slots
  bf16_t* xbf   = (bf16_t*)(lossa + 512 + 294912 + 3548160 + 16384 + 65536); // 65536 slots
  bf16_t* Hbf   = (bf16_t*)(lossa + 512 + 294912 + 3548160 + 16384 + 65536 + 65536); // 524288 slots
  float* R     = lossa + 512 + 294912 + 3548160 + 16384 + 65536 + 65536 + 524288;
  float* Pp    = R;                         // 2 x 524288 (split-K halves)
  float* dA    = Pp   + 2*524288;           // 524288
  float* coef  = dA   + 524288;             // 524288
  float* ypart = R;                         // 32*131072 = 4194304, overlays R
  float* WgdT  = R + 4194304;               // 18432 (past ypart span; no collision)
  float* WdtT  = WgdT + 18432;              // 16384

  k_prep<<<CVT_BLOCKS + W0_BLOCKS + W1_BLOCKS + XB_BLOCKS + WGT_BLOCKS + WDT_BLOCKS,
           256, 0, stream>>>(
      Wg, Wgbf, W0, W0bf, W1, W1bf, x, xbf, Wdt, WdtT, WgdT, lossa);
  k_mlp1m<<<dim3(HID_/64, M_/64), 256, 0, stream>>>(xbf, W0bf, b0, Hbf);
  k_mlp2m<<<dim3(N_/64, M_/64, 2), 256, 0, stream>>>(Hbf, W1bf, b1, Pp);
  k_convdelta<<<M_/4, 256, 0, stream>>>(Pp, u, cw, cb, WgdT, bg, WdtT, bdt, Ap,
                                        oldbf, dA, coef);
  k_bmfma<<<dim3(64, 16), 256, 0, stream>>>(oldbf, Wgbf, bg, u, coef, dA, Pp, zall);
  k_cmfma<<<dim3(32, 16), 256, 0, stream>>>(oldbf, Wgbf, bg, zall, ypart);
  k_finalize<<<512, 256, 0, stream>>>(ypart, x, out, lossa);
}

// Round 15
// 190.242 us; speedup vs baseline: 1.0152x; 1.0152x over previous
//
#include <hip/hip_runtime.h>
#include <math.h>

#define B_   16
#define L_   128
#define O_   128
#define N_   256
#define S_   64
#define U_   32
#define DEL_ 64
#define HID_ 512
#define CH_  288          // N_+U_
#define M_   2048         // B_*L_
#define KD_  288          // GEMM K for the Wg projections
#define CM_BASE (DEL_ + N_*U_)   // 8256
#define NSLICE 32

typedef __bf16 bf16_t;
typedef bf16_t bf16x8 __attribute__((ext_vector_type(8)));
typedef float  f32x4  __attribute__((ext_vector_type(4)));

#define AS1(p) ((const __attribute__((address_space(1))) void*)(unsigned long long)(const void*)(p))
#define AS3(p) ((__attribute__((address_space(3))) void*)(unsigned int)(unsigned long long)(const void*)(p))

__device__ __forceinline__ float silu_f(float x){ return x / (1.f + expf(-x)); }
__device__ __forceinline__ float softplus_f(float x){
  return fmaxf(x, 0.f) + log1pf(expf(-fabsf(x)));
}

__device__ __forceinline__ void cvt8(const float* src, bf16_t* dst){
  float4 a = ((const float4*)src)[0];
  float4 b = ((const float4*)src)[1];
  bf16x8 o;
  o[0]=(bf16_t)a.x; o[1]=(bf16_t)a.y; o[2]=(bf16_t)a.z; o[3]=(bf16_t)a.w;
  o[4]=(bf16_t)b.x; o[5]=(bf16_t)b.y; o[6]=(bf16_t)b.z; o[7]=(bf16_t)b.w;
  *(bf16x8*)dst = o;
}

// ---------------- prep: Wg/W0/W1->bf16, x->bf16 packed, WgdT+WdtT transposes ----------------
#define CVT_BLOCKS 3465    // ceil(887040/256)  (Wg chunks of 8)
#define W0_BLOCKS  16      // 4096 chunks
#define W1_BLOCKS  64      // 16384 chunks
#define XB_BLOCKS  64      // 16384 chunks
#define WGT_BLOCKS 72      // 18432 elements: WgdT[288][64] = Wg[0:64][0:288]^T (delta slice)
#define WDT_BLOCKS 64      // 16384 elements: WdtT[64][256] = Wdt[256][64]^T
__global__ void k_prep(const float* __restrict__ Wg, bf16_t* __restrict__ Wgbf,
                       const float* __restrict__ W0, bf16_t* __restrict__ W0bf,
                       const float* __restrict__ W1, bf16_t* __restrict__ W1bf,
                       const float* __restrict__ x,  bf16_t* __restrict__ xbf,
                       const float* __restrict__ Wdt, float* __restrict__ WdtT,
                       float* __restrict__ WgdT, float* __restrict__ lossa){
  if (blockIdx.x == 0 && threadIdx.x < 2) lossa[threadIdx.x] = 0.f;
  if (blockIdx.x < CVT_BLOCKS) {
    int i = blockIdx.x*256 + threadIdx.x;
    if (i >= 887040) return;
    cvt8(Wg + (size_t)i*8, Wgbf + (size_t)i*8);
  } else if (blockIdx.x < CVT_BLOCKS + W0_BLOCKS) {
    int i = (blockIdx.x - CVT_BLOCKS)*256 + threadIdx.x;
    if (i >= 4096) return;
    cvt8(W0 + (size_t)i*8, W0bf + (size_t)i*8);
  } else if (blockIdx.x < CVT_BLOCKS + W0_BLOCKS + W1_BLOCKS) {
    int i = (blockIdx.x - CVT_BLOCKS - W0_BLOCKS)*256 + threadIdx.x;
    if (i >= 16384) return;
    cvt8(W1 + (size_t)i*8, W1bf + (size_t)i*8);
  } else if (blockIdx.x < CVT_BLOCKS + W0_BLOCKS + W1_BLOCKS + XB_BLOCKS) {
    int i = (blockIdx.x - CVT_BLOCKS - W0_BLOCKS - W1_BLOCKS)*256 + threadIdx.x;
    if (i >= 16384) return;
    int m = i >> 3, c0 = (i & 7)*8;
    int b = m >> 7, t = m & 127;
    cvt8(x + (size_t)(((b<<8)+t)<<6) + c0, xbf + (size_t)m*64 + c0);
  } else if (blockIdx.x < CVT_BLOCKS + W0_BLOCKS + W1_BLOCKS + XB_BLOCKS + WGT_BLOCKS) {
    // delta-slice transpose: WgdT[k][d] = Wg[d][k], d<64, k<288 (coalesced read)
    int i = (blockIdx.x - CVT_BLOCKS - W0_BLOCKS - W1_BLOCKS - XB_BLOCKS)*256 + threadIdx.x;
    if (i >= 18432) return;
    int d = i / KD_, k = i - d*KD_;
    WgdT[k*64 + d] = Wg[(size_t)d*KD_ + k];
  } else {
    // Wdt transpose: WdtT[d][n] = Wdt[n][d] (write coalesced)
    int i = (blockIdx.x - CVT_BLOCKS - W0_BLOCKS - W1_BLOCKS - XB_BLOCKS - WGT_BLOCKS)*256 + threadIdx.x;
    if (i >= 16384) return;
    int d = i >> 8, n = i & 255;
    WdtT[i] = Wdt[(size_t)n*64 + d];
  }
}

// ---- 64-row tile stage, one 16-row group per wave, arbitrary K offset ----
#define STAGE64K(GBASE, ROW0G, STRIDE, KK, LDSP)                                     \
  { const bf16_t* gp_ = (GBASE) + (size_t)((ROW0G) + wave*16 + lm)*(STRIDE) + (KK) + lq*8; \
    __builtin_amdgcn_global_load_lds(AS1(gp_), AS3((LDSP) + wave*512), 16, 0, 0); }

// ---- 64-row tile stage, BK=128 in fragment order (4 k-subblocks of 32) ----
#define STAGE128(GBASE, ROW0G, STRIDE, TT, BUF)                                      \
  { _Pragma("unroll")                                                                \
    for (int kb_ = 0; kb_ < 4; kb_++) {                                              \
      const bf16_t* gp_ = (GBASE) + (size_t)((ROW0G) + wave*16 + lm)*(STRIDE)        \
                          + (TT)*128 + kb_*32 + lq*8;                                \
      __builtin_amdgcn_global_load_lds(AS1(gp_), AS3((BUF) + kb_*2048 + wave*512), 16, 0, 0);\
    } }

// ---- 128-row tile stage, BK=32: two 16-row groups per wave (one 8 KB chunk) ----
#define STAGE32(GBASE, ROW0G, KK, LDSP)                                              \
  { _Pragma("unroll")                                                                \
    for (int l_ = 0; l_ < 2; l_++) {                                                 \
      int g_ = wave*2 + l_;                                                          \
      const bf16_t* gp_ = (GBASE) + (size_t)((ROW0G) + g_*16 + lm)*KD_ + (KK) + lq*8;\
      __builtin_amdgcn_global_load_lds(AS1(gp_), AS3((LDSP) + g_*512), 16, 0, 0);    \
    } }

// ---- 128-row tile stage, BK=96 (3 col-blocks of 32) ----
#define STAGE_FR96(GBASE, ROW0G, KK, LDSP)                                           \
  { _Pragma("unroll")                                                                \
    for (int c_ = 0; c_ < 3; c_++) {                                                 \
      _Pragma("unroll")                                                              \
      for (int q_ = 0; q_ < 2; q_++) {                                               \
        int g_ = wave*2 + q_;                                                        \
        const bf16_t* gp_ = (GBASE) + (size_t)((ROW0G) + g_*16 + lm)*KD_ + (KK) + c_*32 + lq*8;\
        __builtin_amdgcn_global_load_lds(AS1(gp_), AS3((LDSP) + c_*4096 + g_*512), 16, 0, 0);\
      } } }

// ---------------- mlp1 MFMA: Hbf = relu(xbf @ W0bf.T + b0), K=64, 2-phase ----------------
__global__ __launch_bounds__(256) void k_mlp1m(
    const bf16_t* __restrict__ xbf, const bf16_t* __restrict__ W0bf,
    const float* __restrict__ b0, bf16_t* __restrict__ Hbf){
  __shared__ __align__(16) bf16_t As[2][2048];
  __shared__ __align__(16) bf16_t Bs[2][2048];
  int tid = threadIdx.x;
  int wave = tid >> 6, lane = tid & 63;
  int wm = wave & 1, wn = wave >> 1;
  int nt = blockIdx.x, mt = blockIdx.y;
  int m0 = mt*64, n0 = nt*64;
  int lm = lane & 15, lq = lane >> 4;

  f32x4 acc[2][2];
  #pragma unroll
  for (int i=0;i<2;i++)
    #pragma unroll
    for (int j=0;j<2;j++){ acc[i][j][0]=0.f;acc[i][j][1]=0.f;acc[i][j][2]=0.f;acc[i][j][3]=0.f; }

  STAGE64K(xbf,  m0, 64, 0, As[0]);
  STAGE64K(W0bf, n0, 64, 0, Bs[0]);
  __syncthreads();
  #pragma unroll
  for (int t = 0; t < 2; ++t) {
    int cur = t & 1;
    if (t < 1) {
      STAGE64K(xbf,  m0, 64, 32, As[1]);
      STAGE64K(W0bf, n0, 64, 32, Bs[1]);
    }
    bf16x8 af[2], bff[2];
    #pragma unroll
    for (int i=0;i<2;i++) af[i]  = *(const bf16x8*)&As[cur][(wm*2 + i)*512 + lane*8];
    #pragma unroll
    for (int j=0;j<2;j++) bff[j] = *(const bf16x8*)&Bs[cur][(wn*2 + j)*512 + lane*8];
    #pragma unroll
    for (int i=0;i<2;i++)
      #pragma unroll
      for (int j=0;j<2;j++)
        acc[i][j] = __builtin_amdgcn_mfma_f32_16x16x32_bf16(af[i], bff[j], acc[i][j], 0,0,0);
    __syncthreads();
  }
  #pragma unroll
  for (int i=0;i<2;i++)
    #pragma unroll
    for (int j=0;j<2;j++){
      int col = n0 + wn*32 + j*16 + lm;
      float bb = b0[col];
      #pragma unroll
      for (int r=0;r<4;r++){
        int row = m0 + wm*32 + i*16 + lq*4 + r;
        Hbf[(size_t)row*HID_ + col] = (bf16_t)fmaxf(acc[i][j][r] + bb, 0.f);
      }
    }
}

// ---------------- mlp2 MFMA: P = Hbf @ W1bf.T + b1, K=512, BK=128, 4-step dbuf ----------------
__global__ __launch_bounds__(256) void k_mlp2m(
    const bf16_t* __restrict__ Hbf, const bf16_t* __restrict__ W1bf,
    const float* __restrict__ b1, float* __restrict__ P){
  __shared__ __align__(16) bf16_t As[2][8192];
  __shared__ __align__(16) bf16_t Bs[2][8192];
  int tid = threadIdx.x;
  int wave = tid >> 6, lane = tid & 63;
  int wm = wave & 1, wn = wave >> 1;
  int nt = blockIdx.x, mt = blockIdx.y;
  int m0 = mt*64, n0 = nt*64;
  int lm = lane & 15, lq = lane >> 4;

  f32x4 acc[2][2];
  #pragma unroll
  for (int i=0;i<2;i++)
    #pragma unroll
    for (int j=0;j<2;j++){ acc[i][j][0]=0.f;acc[i][j][1]=0.f;acc[i][j][2]=0.f;acc[i][j][3]=0.f; }

  STAGE128(Hbf,  m0, HID_, 0, As[0]);
  STAGE128(W1bf, n0, HID_, 0, Bs[0]);
  __syncthreads();
  #pragma unroll
  for (int t = 0; t < 4; ++t) {
    int cur = t & 1;
    if (t < 3) {
      STAGE128(Hbf,  m0, HID_, t+1, As[cur^1]);
      STAGE128(W1bf, n0, HID_, t+1, Bs[cur^1]);
    }
    #pragma unroll
    for (int kb = 0; kb < 4; kb++) {
      bf16x8 af[2], bff[2];
      #pragma unroll
      for (int i=0;i<2;i++) af[i]  = *(const bf16x8*)&As[cur][kb*2048 + (wm*2 + i)*512 + lane*8];
      #pragma unroll
      for (int j=0;j<2;j++) bff[j] = *(const bf16x8*)&Bs[cur][kb*2048 + (wn*2 + j)*512 + lane*8];
      #pragma unroll
      for (int i=0;i<2;i++)
        #pragma unroll
        for (int j=0;j<2;j++)
          acc[i][j] = __builtin_amdgcn_mfma_f32_16x16x32_bf16(af[i], bff[j], acc[i][j], 0,0,0);
    }
    __syncthreads();
  }
  #pragma unroll
  for (int i=0;i<2;i++)
    #pragma unroll
    for (int j=0;j<2;j++){
      int col = n0 + wn*32 + j*16 + lm;
      float bb = b1[col];
      #pragma unroll
      for (int r=0;r<4;r++){
        int row = m0 + wm*32 + i*16 + lq*4 + r;
        P[(size_t)row*N_ + col] = acc[i][j][r] + bb;
      }
    }
}

// ---------------- fused conv + delta, 4 rows/block (512 blocks) ----------------
__global__ __launch_bounds__(256) void k_convdelta(
    const float* __restrict__ P, const float* __restrict__ u,
    const float* __restrict__ cw, const float* __restrict__ cb,
    const float* __restrict__ WgdT, const float* __restrict__ bg,
    const float* __restrict__ WdtT, const float* __restrict__ bdt,
    const float* __restrict__ Ap, bf16_t* __restrict__ oldbf,
    float* __restrict__ dA, float* __restrict__ coef){
  __shared__ __align__(16) float olds[4*KD_];
  __shared__ float dr[4][64];
  int tid = threadIdx.x;
  int m0 = blockIdx.x * 4;
  int b = m0 >> 7, l0 = m0 & 127;
  for (int e = tid; e < 4*CH_; e += 256) {
    int r = e / CH_, c = e - r*CH_;
    int l = l0 + r;
    float acc = cb[c];
    #pragma unroll
    for (int k = 0; k < 4; k++) {
      int t = l + k - 1;
      if (t >= 0 && t <= O_-2) {
        float s = (c < N_) ? P[((b<<7)+t)*N_ + c] : u[((b<<8)+t)*U_ + (c-N_)];
        acc += silu_f(s) * cw[c*4 + k];
      }
    }
    float v = silu_f(acc);
    olds[e] = v;
    oldbf[(size_t)(m0+r)*CH_ + c] = (bf16_t)v;
  }
  __syncthreads();
  {
    int d = tid & 63;
    int r = tid >> 6;
    const float* wcol = WgdT + d;          // column d of WgdT[288][64]
    const float* orow = olds + r*KD_;
    float s = 0.f;
    for (int k = 0; k < KD_; k++) s += orow[k] * wcol[k*64];   // lanes coalesce per k
    dr[r][d] = s + bg[d];
  }
  __syncthreads();
  int n = tid;
  float wrow[64];
  #pragma unroll
  for (int d = 0; d < 64; d++) wrow[d] = WdtT[d*256 + n];   // coalesced: lanes consecutive
  float a0 = Ap[n];
  float a = -(a0 > 0.f ? a0 : expm1f(a0));
  float inva = 1.f / a;
  float bd = bdt[n];
  #pragma unroll
  for (int r = 0; r < 4; r++) {
    float s = bd;
    #pragma unroll
    for (int d = 0; d < 64; d++) s += dr[r][d] * wrow[d];   // dr: wave-broadcast
    float dd = softplus_f(s);
    float e  = expf(dd * a);
    size_t m = m0 + r;
    dA[m*N_ + n]   = e;
    coef[m*N_ + n] = (e - 1.f) * inva;
  }
}

// ---------------- B-path MFMA v3b: ring-3 counted-vmcnt, LDS 48 KB, LB(256,2) ----------------
// Ring-3 schedule; launch bounds (256,2) keeps natural ~112 VGPR (no spills).
// LDS 48 KB lets HW reach 3 blocks/CU on its own.
__global__ __launch_bounds__(256, 2) void k_bmfma(
    const bf16_t* __restrict__ oldbf, const bf16_t* __restrict__ Wgbf,
    const float* __restrict__ bg, const float* __restrict__ u,
    const float* __restrict__ coef, const float* __restrict__ dAg,
    const float* __restrict__ Pg, float* __restrict__ zall){
  __shared__ union {
    struct { __align__(16) bf16_t A[3][4096]; __align__(16) bf16_t B[3][4096]; } st; // 48 KB
    struct { float wl[128][4]; float dal[128][4]; } sc;   // 4 KB, used post-GEMM
  } sm;
  int tid = threadIdx.x;
  int wave = tid >> 6, lane = tid & 63;
  int wm = wave & 1, wn = wave >> 1;
  int mt = blockIdx.y, nt = blockIdx.x;
  int m0 = mt*128, ncol0 = nt*128;
  int lm = lane & 15, lq = lane >> 4;

  f32x4 acc[4][4];
  #pragma unroll
  for (int i=0;i<4;i++)
    #pragma unroll
    for (int j=0;j<4;j++){ acc[i][j][0]=0.f;acc[i][j][1]=0.f;acc[i][j][2]=0.f;acc[i][j][3]=0.f; }

  // prologue: issue steps 0,1 (8 loads in flight)
  STAGE32(oldbf, m0, 0, sm.st.A[0]);
  STAGE32(Wgbf, DEL_ + ncol0, 0, sm.st.B[0]);
  STAGE32(oldbf, m0, 32, sm.st.A[1]);
  STAGE32(Wgbf, DEL_ + ncol0, 32, sm.st.B[1]);
  #pragma unroll
  for (int t = 0; t < 9; ++t) {             // 288/32 = 9 K-steps
    if (t < 8) { asm volatile("s_waitcnt vmcnt(4)" ::: "memory"); }  // step t done, t+1 in flight
    else       { asm volatile("s_waitcnt vmcnt(0)" ::: "memory"); }
    __builtin_amdgcn_s_barrier();           // step t visible; slot (t+2)%3 readers done
    if (t + 2 < 9) {                        // issue step t+2 into ring slot
      int kk = (t+2)*32;
      STAGE32(oldbf, m0, kk, sm.st.A[(t+2)%3]);
      STAGE32(Wgbf, DEL_ + ncol0, kk, sm.st.B[(t+2)%3]);
    }
    bf16x8 af[4], bff[4];
    #pragma unroll
    for (int i=0;i<4;i++) af[i]  = *(const bf16x8*)&sm.st.A[t%3][(wm*4 + i)*512 + lane*8];
    #pragma unroll
    for (int j=0;j<4;j++) bff[j] = *(const bf16x8*)&sm.st.B[t%3][(wn*4 + j)*512 + lane*8];
    __builtin_amdgcn_s_setprio(1);          // T5: favor MFMA-issuing wave
    #pragma unroll
    for (int i=0;i<4;i++)
      #pragma unroll
      for (int j=0;j<4;j++)
        acc[i][j] = __builtin_amdgcn_mfma_f32_16x16x32_bf16(af[i], bff[j], acc[i][j], 0,0,0);
    __builtin_amdgcn_s_setprio(0);
  }
  __syncthreads();                          // all st readers done before sc overlay

  // staging LDS dead: preload dA columns for the fused scan
  for (int e = tid; e < 512; e += 256)
    sm.sc.dal[e>>2][e&3] = dAg[(size_t)(m0 + (e>>2))*N_ + nt*4 + (e&3)];

  float bgv[4];
  #pragma unroll
  for (int j=0;j<4;j++) bgv[j] = bg[DEL_ + ncol0 + wn*64 + j*16 + lm];
  float p[2][4][4];
  #pragma unroll
  for (int a=0;a<2;a++)
    #pragma unroll
    for (int i=0;i<4;i++)
      #pragma unroll
      for (int r=0;r<4;r++) p[a][i][r]=0.f;
  #pragma unroll
  for (int i=0;i<4;i++){
    #pragma unroll
    for (int r=0;r<4;r++){
      int m = m0 + wm*64 + i*16 + lq*4 + r;
      int b = m >> 7, l = m & 127;
      const float* urow = u + ((size_t)(b<<8) + 127 + l)*U_;
      #pragma unroll
      for (int j=0;j<4;j++){
        float uu = urow[(j&1)*16 + lm];
        p[j>>1][i][r] += (acc[i][j][r] + bgv[j]) * uu;
      }
    }
  }
  #pragma unroll
  for (int mk = 1; mk < 16; mk <<= 1){
    #pragma unroll
    for (int a=0;a<2;a++)
      #pragma unroll
      for (int i=0;i<4;i++)
        #pragma unroll
        for (int r=0;r<4;r++) p[a][i][r] += __shfl_xor(p[a][i][r], mk);
  }
  if (lm == 0){
    #pragma unroll
    for (int nl=0;nl<2;nl++){
      int n = ((ncol0 + wn*64 + nl*32) >> 5);
      int nc = wn*2 + nl;
      #pragma unroll
      for (int i=0;i<4;i++)
        #pragma unroll
        for (int r=0;r<4;r++){
          int l = wm*64 + i*16 + lq*4 + r;
          sm.sc.wl[l][nc] = coef[(size_t)(m0+l)*N_ + n] * p[nl][i][r];
        }
    }
  }
  __syncthreads();

  // fused scan: wave = n-column; 2 l per lane, Kogge-Stone over pair affines
  {
    int nc = wave;
    int n = nt*4 + nc;
    float z0 = Pg[(size_t)(m0 + 127)*N_ + n];
    int l0 = lane*2;
    float a0 = sm.sc.dal[l0][nc],   w0 = sm.sc.wl[l0][nc];
    float a1 = sm.sc.dal[l0+1][nc], w1 = sm.sc.wl[l0+1][nc];
    float A = a0*a1, Bv = w0*a1 + w1;
    #pragma unroll
    for (int d = 1; d < 64; d <<= 1){
      float Ap = __shfl_up(A, d);
      float Bp = __shfl_up(Bv, d);
      if (lane >= d){ Bv = Bp*A + Bv; A = Ap*A; }
    }
    float Ae = __shfl_up(A, 1);
    float Be = __shfl_up(Bv, 1);
    if (lane == 0){ Ae = 1.f; Be = 0.f; }
    float zp = z0*Ae + Be;
    float za = zp*a0 + w0;
    float zb = za*a1 + w1;
    zall[(size_t)(m0 + l0)*N_ + n]     = za;
    zall[(size_t)(m0 + l0 + 1)*N_ + n] = zb;
  }
}

// ---------------- C-path MFMA v7b: ring-3 counted-vmcnt, LDS 52 KB, LB(256,2) ----------------
// Ring-3 schedule with launch bounds (256,2) (VGPR ~112, no spills).
// 52 KB LDS -> HW occupancy 3 blocks/CU without register squeeze.
__global__ __launch_bounds__(256, 2) void k_cmfma(
    const bf16_t* __restrict__ oldbf, const bf16_t* __restrict__ Wgbf,
    const float* __restrict__ bg, const float* __restrict__ zall,
    float* __restrict__ ypart){
  __shared__ union {
    struct { __align__(16) bf16_t A[3*4096];   // 24 KB, resident per kh
             __align__(16) bf16_t Bb[3][4096]; // 24 KB, 3-deep chunk ring
             float zl[128][8]; } st;           // 4 KB  -> 52 KB total
    float ylds[128][64];                        // 32 KB, used at the end
  } sm;
  int tid = threadIdx.x;
  int wave = tid >> 6, lane = tid & 63;
  int wm = wave & 1, wn = wave >> 1;
  int mt = blockIdx.y, grp = blockIdx.x;   // 32 groups of 4 n-tiles
  int m0 = mt*128;
  int lm = lane & 15, lq = lane >> 4;

  // preload z block: 128 m x 8 n
  for (int e = tid; e < 1024; e += 256)
    sm.st.zl[e>>3][e&7] = zall[(size_t)(m0 + (e>>3))*N_ + grp*8 + (e&7)];

  f32x4 yacc[4][4];
  #pragma unroll
  for (int i=0;i<4;i++)
    #pragma unroll
    for (int j=0;j<4;j++){ yacc[i][j][0]=0.f;yacc[i][j][1]=0.f;yacc[i][j][2]=0.f;yacc[i][j][3]=0.f; }

  f32x4 acc[4][4];
  for (int kh = 0; kh < 3; kh++) {
    int kk = kh*96;
    if (kh) __builtin_amdgcn_s_barrier();        // all A/Bb readers of prev kh done
    STAGE_FR96(oldbf, m0, kk, sm.st.A);          // 6 loads
    STAGE32(Wgbf, CM_BASE + (grp*4)*128, kk,      sm.st.Bb[0]);  // chunk 0 (2 loads)
    STAGE32(Wgbf, CM_BASE + (grp*4)*128, kk + 32, sm.st.Bb[1]);  // chunk 1 (2 loads)

    #pragma unroll
    for (int c = 0; c < 12; ++c) {               // chunk = (it = c/3, cb = c%3)
      int it = c/3, cb = c%3;
      // c=0: completes A+chunk0 (chunk1 in flight); c=1..10: completes chunk c; c=11: drain
      if (c < 11) { asm volatile("s_waitcnt vmcnt(2)" ::: "memory"); }
      else        { asm volatile("s_waitcnt vmcnt(0)" ::: "memory"); }
      __builtin_amdgcn_s_barrier();              // chunk c visible; slot (c+2)%3 readers done
      if (c + 2 < 12) {
        int c2 = c + 2, it2 = c2/3, cb2 = c2%3;
        STAGE32(Wgbf, CM_BASE + (grp*4 + it2)*128, kk + cb2*32, sm.st.Bb[c2 % 3]);
      }
      if (cb == 0) {
        #pragma unroll
        for (int i=0;i<4;i++)
          #pragma unroll
          for (int j=0;j<4;j++){ acc[i][j][0]=0.f;acc[i][j][1]=0.f;acc[i][j][2]=0.f;acc[i][j][3]=0.f; }
      }
      bf16x8 af[4], bff[4];
      #pragma unroll
      for (int i=0;i<4;i++) af[i]  = *(const bf16x8*)&sm.st.A[cb*4096 + (wm*4 + i)*512 + lane*8];
      #pragma unroll
      for (int j=0;j<4;j++) bff[j] = *(const bf16x8*)&sm.st.Bb[c % 3][(wn*4 + j)*512 + lane*8];
      __builtin_amdgcn_s_setprio(1);
      #pragma unroll
      for (int i=0;i<4;i++)
        #pragma unroll
        for (int j=0;j<4;j++)
          acc[i][j] = __builtin_amdgcn_mfma_f32_16x16x32_bf16(af[i], bff[j], acc[i][j], 0,0,0);
      __builtin_amdgcn_s_setprio(0);
      if (cb == 2) {
        // it's full-K gen tile done: contract with z (bg only on last kh)
        int ncol0 = (grp*4 + it)*128;
        int nl = it*2 + wn;
        float bgv[4];
        #pragma unroll
        for (int j=0;j<4;j++)
          bgv[j] = (kh == 2) ? bg[CM_BASE + ncol0 + wn*64 + j*16 + lm] : 0.f;
        #pragma unroll
        for (int i=0;i<4;i++){
          #pragma unroll
          for (int r=0;r<4;r++){
            float zv = sm.st.zl[wm*64 + i*16 + lq*4 + r][nl];
            #pragma unroll
            for (int j=0;j<4;j++)
              yacc[i][j][r] += (acc[i][j][r] + bgv[j]) * zv;
          }
        }
      }
    }
  }

  __builtin_amdgcn_s_barrier();   // all st readers done before ylds overlay
  // merge the two wn halves through ylds (overlays staging LDS), then store slice
  if (wn == 1){
    #pragma unroll
    for (int i=0;i<4;i++)
      #pragma unroll
      for (int j=0;j<4;j++)
        #pragma unroll
        for (int r=0;r<4;r++){
          int ml = wm*64 + i*16 + lq*4 + r;
          sm.ylds[ml][j*16 + lm] = yacc[i][j][r];
        }
  }
  __syncthreads();
  if (wn == 0){
    float* dst = ypart + (size_t)grp*(M_*S_);
    #pragma unroll
    for (int i=0;i<4;i++)
      #pragma unroll
      for (int j=0;j<4;j++)
        #pragma unroll
        for (int r=0;r<4;r++){
          int ml = wm*64 + i*16 + lq*4 + r;
          int s = j*16 + lm;
          dst[(size_t)(m0+ml)*S_ + s] = yacc[i][j][r] + sm.ylds[ml][s];
        }
  }
}

// ---------------- finalize: sum slices, write ys (L,B,S), fused loss ----------------
__global__ void k_finalize(const float* __restrict__ ypart, const float* __restrict__ x,
                           float* __restrict__ out, float* __restrict__ lossacc){
  __shared__ float red[256];
  int tid = threadIdx.x;
  float ls = 0.f;
  #pragma unroll
  for (int q = 0; q < 2; q++) {
    int e = blockIdx.x*512 + q*256 + tid;
    int m = e >> 6, s = e & 63;
    int b = m >> 7, l = m & 127;
    float yv = 0.f;
    #pragma unroll 8
    for (int g = 0; g < NSLICE; g++) yv += ypart[(size_t)g*(M_*S_) + e];
    out[1 + (size_t)((l<<4) + b)*S_ + s] = yv;
    float xv = x[((size_t)(b<<8) + 128 + l)*S_ + s];
    float d = yv - xv;
    ls += d*d;
  }
  red[tid] = ls; __syncthreads();
  for (int st = 128; st > 0; st >>= 1) {
    if (tid < st) red[tid] += red[tid+st];
    __syncthreads();
  }
  if (tid == 0) {
    atomicAdd(&lossacc[0], red[0]);
    __threadfence();
    unsigned old = atomicAdd((unsigned*)&lossacc[1], 1u);
    if (old == 255u) {
      float tot = atomicAdd(&lossacc[0], 0.f);   // atomic read (bypass L1)
      out[0] = tot * (1.f / (float)(B_*S_*L_));
    }
  }
}

extern "C" void kernel_launch(void* const* d_in, const int* in_sizes, int n_in,
                              void* d_out, int out_size, void* d_ws, size_t ws_size,
                              hipStream_t stream) {
  const float* x   = (const float*)d_in[0];
  const float* u   = (const float*)d_in[1];
  const float* Ap  = (const float*)d_in[2];
  const float* W0  = (const float*)d_in[3];
  const float* b0  = (const float*)d_in[4];
  const float* W1  = (const float*)d_in[5];
  const float* b1  = (const float*)d_in[6];
  const float* cw  = (const float*)d_in[7];
  const float* cb  = (const float*)d_in[8];
  const float* Wg  = (const float*)d_in[9];
  const float* bg  = (const float*)d_in[10];
  const float* Wdt = (const float*)d_in[11];
  const float* bdt = (const float*)d_in[12];
  float* out = (float*)d_out;

  // Layout: persistent buffers first; region R of fp32 temps (all dead before
  // k_cmfma) is overlaid by ypart (32 slices = 16 MB). WgdT/WdtT past ypart's span.
  float* ws    = (float*)d_ws;
  float* zall  = ws;                        // 524288
  float* lossa = zall + 524288;             // 512 (acc, counter)
  bf16_t* oldbf = (bf16_t*)(lossa + 512);   // 294912 f32 slots
  bf16_t* Wgbf  = (bf16_t*)(lossa + 512 + 294912);              // 3548160 slots
  bf16_t* W0bf  = (bf16_t*)(lossa + 512 + 294912 + 3548160);    // 16384 slots
  bf16_t* W1bf  = (bf16_t*)(lossa + 512 + 294912 + 3548160 + 16384);   // 65536 slots
  bf16_t* xbf   = (bf16_t*)(lossa + 512 + 294912 + 3548160 + 16384 + 65536); // 65536 slots
  bf16_t* Hbf   = (bf16_t*)(lossa + 512 + 294912 + 3548160 + 16384 + 65536 + 65536); // 524288 slots
  float* R     = lossa + 512 + 294912 + 3548160 + 16384 + 65536 + 65536 + 524288;
  float* Pp    = R;                         // 524288
  float* dA    = Pp   + 524288;             // 524288
  float* coef  = dA   + 524288;             // 524288
  float* ypart = R;                         // 32*131072 = 4194304, overlays R
  float* WgdT  = R + 4194304;               // 18432 (past ypart span; no collision)
  float* WdtT  = WgdT + 18432;              // 16384

  k_prep<<<CVT_BLOCKS + W0_BLOCKS + W1_BLOCKS + XB_BLOCKS + WGT_BLOCKS + WDT_BLOCKS,
           256, 0, stream>>>(
      Wg, Wgbf, W0, W0bf, W1, W1bf, x, xbf, Wdt, WdtT, WgdT, lossa);
  k_mlp1m<<<dim3(HID_/64, M_/64), 256, 0, stream>>>(xbf, W0bf, b0, Hbf);
  k_mlp2m<<<dim3(N_/64, M_/64), 256, 0, stream>>>(Hbf, W1bf, b1, Pp);
  k_convdelta<<<M_/4, 256, 0, stream>>>(Pp, u, cw, cb, WgdT, bg, WdtT, bdt, Ap,
                                        oldbf, dA, coef);
  k_bmfma<<<dim3(64, 16), 256, 0, stream>>>(oldbf, Wgbf, bg, u, coef, dA, Pp, zall);
  k_cmfma<<<dim3(32, 16), 256, 0, stream>>>(oldbf, Wgbf, bg, zall, ypart);
  k_finalize<<<256, 256, 0, stream>>>(ypart, x, out, lossa);
}